// Round 5
// baseline (39.145 us; speedup 1.0000x reference)
//
#include <hip/hip_runtime.h>
#include <hip/hip_cooperative_groups.h>

namespace cg = cooperative_groups;

#define BB 2
#define CC 4
#define TT 128
#define VV 67
#define FF 64
#define NCLS 100
#define TV 8576    // T*V == V*T
#define QQ 134     // TV / FF  (also TV / 64)
#define GB 8       // blocks per batch
#define NTH 256    // threads per block
#define P4 (TV / 4)   // 2144 float4 per channel plane
#define SLOTF 408  // padded per-block slot size in floats (403 used)

__device__ __forceinline__ float agent_load(const float* p) {
    return __hip_atomic_load(p, __ATOMIC_RELAXED, __HIP_MEMORY_SCOPE_AGENT);
}
__device__ __forceinline__ void agent_store(float* p, float v) {
    __hip_atomic_store(p, v, __ATOMIC_RELAXED, __HIP_MEMORY_SCOPE_AGENT);
}

// Whole model, one cooperative kernel.
// Math (batch-separable, rank-1 scores since z >= 0):
//   z[p]  : p = v*128 + t
//   A[q]  = sum_f wth[f] * z[f*QQ + q]            (q = p % 134, f = p / 134)
//   Zp[q'] = sum_k max(wvd[k],0) * z[64 q' + k]   (q' = p >> 6, k = p & 63)
//   Zn[q'] = sum_k min(wvd[k],0) * z[64 q' + k]
//   S     = sum_q A[q] * (A[q] >= 0 ? Zp[q] : Zn[q])    == sum_j relu(wvd*A)*z
//   pooled[c] = Zmean*(S*gw[c]+1) + convh_b[c],  gw[c] = sum_f convh_w[c,f]*wg[f]
//   logits -> softmax -> out
__global__ __launch_bounds__(NTH) void ar_coop(
    const float* __restrict__ joint, const float* __restrict__ vel,
    const float* __restrict__ vc1_w, const float* __restrict__ vc1_b,
    const float* __restrict__ vc2_w, const float* __restrict__ vc2_b,
    const float* __restrict__ sc1_w, const float* __restrict__ sc1_b,
    const float* __restrict__ sc2_w, const float* __restrict__ sc2_b,
    const float* __restrict__ w_theta, const float* __restrict__ w_void,
    const float* __restrict__ w_g,
    const float* __restrict__ convh_w, const float* __restrict__ convh_b,
    const float* __restrict__ lin_w, const float* __restrict__ lin_b,
    float* __restrict__ out, float* __restrict__ ws)
{
    const int blk = blockIdx.x;      // 0..2*GB-1
    const int b = blk / GB;
    const int g = blk % GB;
    const int tid = threadIdx.x;
    const int lane = tid & 63, wave = tid >> 6;

    __shared__ float Ap[QQ], Zp[QQ], Zn[QQ];
    __shared__ float wth[FF], wvp[FF], wvn[FF];
    __shared__ float Zs;
    __shared__ float rs[4], rz[4];
    __shared__ float Svv, Zmm;
    __shared__ float pooled[CC];
    __shared__ float logits[NCLS], evals[NCLS];
    __shared__ float smax, sinv;

    // ---- init LDS ----
    for (int i = tid; i < QQ; i += NTH) { Ap[i] = 0.f; Zp[i] = 0.f; Zn[i] = 0.f; }
    if (tid == 0) Zs = 0.f;
    if (tid < FF) {
        float w = w_void[tid];
        wvp[tid] = fmaxf(w, 0.f);
        wvn[tid] = fminf(w, 0.f);
        wth[tid] = w_theta[tid];
    }
    __syncthreads();

    // scalar 1x1-conv weights (wave-uniform)
    const float v1w0 = vc1_w[0], v1w1 = vc1_w[1], v1w2 = vc1_w[2], v1w3 = vc1_w[3];
    const float s1w0 = sc1_w[0], s1w1 = sc1_w[1], s1w2 = sc1_w[2], s1w3 = sc1_w[3];
    const float v1b = vc1_b[0], v2w = vc2_w[0], v2b = vc2_b[0];
    const float s1b = sc1_b[0], s2w = sc2_w[0], s2b = sc2_b[0];

    // ---- Stage 1: chunked z computation + per-block partials ----
    const float4* velb = (const float4*)(vel + (size_t)b * CC * TV);
    const float4* jntb = (const float4*)(joint + (size_t)b * CC * TV);

    float zacc = 0.f;
    for (int i = g * NTH + tid; i < P4; i += GB * NTH) {
        float4 vA = velb[i];            float4 jA = jntb[i];
        float4 vB = velb[i + P4];       float4 jB = jntb[i + P4];
        float4 vC = velb[i + 2 * P4];   float4 jC = jntb[i + 2 * P4];
        float4 vD = velb[i + 3 * P4];   float4 jD = jntb[i + 3 * P4];

        float zv[4];
        {
            float vs, js;
            vs = v1b + vA.x * v1w0 + vB.x * v1w1 + vC.x * v1w2 + vD.x * v1w3;
            js = s1b + jA.x * s1w0 + jB.x * s1w1 + jC.x * s1w2 + jD.x * s1w3;
            zv[0] = fmaxf(v2w * vs + v2b, 0.f) + fmaxf(s2w * js + s2b, 0.f);
            vs = v1b + vA.y * v1w0 + vB.y * v1w1 + vC.y * v1w2 + vD.y * v1w3;
            js = s1b + jA.y * s1w0 + jB.y * s1w1 + jC.y * s1w2 + jD.y * s1w3;
            zv[1] = fmaxf(v2w * vs + v2b, 0.f) + fmaxf(s2w * js + s2b, 0.f);
            vs = v1b + vA.z * v1w0 + vB.z * v1w1 + vC.z * v1w2 + vD.z * v1w3;
            js = s1b + jA.z * s1w0 + jB.z * s1w1 + jC.z * s1w2 + jD.z * s1w3;
            zv[2] = fmaxf(v2w * vs + v2b, 0.f) + fmaxf(s2w * js + s2b, 0.f);
            vs = v1b + vA.w * v1w0 + vB.w * v1w1 + vC.w * v1w2 + vD.w * v1w3;
            js = s1b + jA.w * s1w0 + jB.w * s1w1 + jC.w * s1w2 + jD.w * s1w3;
            zv[3] = fmaxf(v2w * vs + v2b, 0.f) + fmaxf(s2w * js + s2b, 0.f);
        }

        int r = 4 * i;
        int t = r / VV, v = r - t * VV;
        #pragma unroll
        for (int k = 0; k < 4; ++k) {
            int p = (v << 7) + t;
            float zz = zv[k];
            atomicAdd(&Ap[p % QQ], wth[p / QQ] * zz);
            atomicAdd(&Zp[p >> 6], wvp[p & 63] * zz);
            atomicAdd(&Zn[p >> 6], wvn[p & 63] * zz);
            zacc += zz;
            if (++v == VV) { v = 0; ++t; }
        }
    }
    #pragma unroll
    for (int off = 32; off > 0; off >>= 1) zacc += __shfl_down(zacc, off);
    if (lane == 0) atomicAdd(&Zs, zacc);
    __syncthreads();

    // ---- write this block's partial slot (agent scope for cross-XCD) ----
    float* slot = ws + (size_t)blk * SLOTF;
    for (int i = tid; i < QQ; i += NTH) {
        agent_store(slot + i,          Ap[i]);
        agent_store(slot + QQ + i,     Zp[i]);
        agent_store(slot + 2 * QQ + i, Zn[i]);
    }
    if (tid == 0) agent_store(slot + 3 * QQ, Zs);

    cg::this_grid().sync();

    // ---- Stage 2: two finisher blocks (g == 0), one per batch ----
    if (g != 0) return;

    const float* base = ws + (size_t)b * GB * SLOTF;
    float sq = 0.f, zq = 0.f;
    if (tid < QQ) {
        float a = 0.f, zp = 0.f, zn = 0.f;
        #pragma unroll
        for (int gg = 0; gg < GB; ++gg) {
            const float* sl = base + gg * SLOTF;
            a  += agent_load(sl + tid);
            zp += agent_load(sl + QQ + tid);
            zn += agent_load(sl + 2 * QQ + tid);
        }
        sq = a * (a >= 0.f ? zp : zn);
    }
    if (tid < GB) zq = agent_load(base + tid * SLOTF + 3 * QQ);

    #pragma unroll
    for (int off = 32; off > 0; off >>= 1) {
        sq += __shfl_down(sq, off);
        zq += __shfl_down(zq, off);
    }
    if (lane == 0) { rs[wave] = sq; rz[wave] = zq; }
    __syncthreads();
    if (tid == 0) {
        Svv = rs[0] + rs[1] + rs[2] + rs[3];
        Zmm = (rz[0] + rz[1] + rz[2] + rz[3]) / (float)TV;
    }
    __syncthreads();

    // gw[c] = sum_f convh_w[c,f]*w_g[f]; wave c computes one c
    {
        float gv = convh_w[wave * FF + lane] * w_g[lane];
        #pragma unroll
        for (int off = 32; off > 0; off >>= 1) gv += __shfl_down(gv, off);
        if (lane == 0) pooled[wave] = Zmm * (Svv * gv + 1.0f) + convh_b[wave];
    }
    __syncthreads();

    if (tid < NCLS) {
        float lg = lin_b[tid];
        #pragma unroll
        for (int c = 0; c < CC; ++c) lg += lin_w[tid * CC + c] * pooled[c];
        logits[tid] = lg;
    }
    __syncthreads();
    if (wave == 0) {
        float m = -1e30f;
        for (int n = lane; n < NCLS; n += 64) m = fmaxf(m, logits[n]);
        #pragma unroll
        for (int off = 32; off > 0; off >>= 1) m = fmaxf(m, __shfl_down(m, off));
        if (lane == 0) smax = m;
    }
    __syncthreads();
    if (tid < NCLS) evals[tid] = expf(logits[tid] - smax);
    __syncthreads();
    if (wave == 0) {
        float s = 0.f;
        for (int n = lane; n < NCLS; n += 64) s += evals[n];
        #pragma unroll
        for (int off = 32; off > 0; off >>= 1) s += __shfl_down(s, off);
        if (lane == 0) sinv = 1.0f / s;
    }
    __syncthreads();
    if (tid < NCLS) out[b * NCLS + tid] = evals[tid] * sinv;
}

extern "C" void kernel_launch(void* const* d_in, const int* in_sizes, int n_in,
                              void* d_out, int out_size, void* d_ws, size_t ws_size,
                              hipStream_t stream) {
    const float* joint  = (const float*)d_in[0];
    const float* vel    = (const float*)d_in[1];
    const float* vc1_w  = (const float*)d_in[2];
    const float* vc1_b  = (const float*)d_in[3];
    const float* vc2_w  = (const float*)d_in[4];
    const float* vc2_b  = (const float*)d_in[5];
    const float* sc1_w  = (const float*)d_in[6];
    const float* sc1_b  = (const float*)d_in[7];
    const float* sc2_w  = (const float*)d_in[8];
    const float* sc2_b  = (const float*)d_in[9];
    const float* w_theta = (const float*)d_in[10];
    const float* w_void  = (const float*)d_in[11];
    const float* w_g     = (const float*)d_in[12];
    const float* convh_w = (const float*)d_in[13];
    const float* convh_b = (const float*)d_in[14];
    const float* lin_w   = (const float*)d_in[15];
    const float* lin_b   = (const float*)d_in[16];
    float* out = (float*)d_out;
    float* ws  = (float*)d_ws;

    void* args[] = {
        (void*)&joint, (void*)&vel,
        (void*)&vc1_w, (void*)&vc1_b, (void*)&vc2_w, (void*)&vc2_b,
        (void*)&sc1_w, (void*)&sc1_b, (void*)&sc2_w, (void*)&sc2_b,
        (void*)&w_theta, (void*)&w_void, (void*)&w_g,
        (void*)&convh_w, (void*)&convh_b, (void*)&lin_w, (void*)&lin_b,
        (void*)&out, (void*)&ws
    };
    hipLaunchCooperativeKernel((const void*)ar_coop, dim3(BB * GB), dim3(NTH),
                               args, 0, stream);
}

// Round 6
// 14.967 us; speedup vs baseline: 2.6155x; 2.6155x over previous
//
#include <hip/hip_runtime.h>

#define BB 2
#define CC 4
#define TT 128
#define VV 67
#define FF 64
#define NCLS 100
#define TV 8576        // T*V == V*T
#define QQ 134         // TV/64 == TV/134*... (TV = 134*64)
#define GB 8           // blocks per batch
#define NTH 256
#define P4 (TV / 4)    // 2144 float4 per channel plane
#define CHUNK (P4 / GB) // 268
#define SLOTF 408      // padded slot (403 used)
#define POISON 0xAAAAAAAAu

__device__ __forceinline__ float agent_loadf(const float* p) {
    return __hip_atomic_load(p, __ATOMIC_RELAXED, __HIP_MEMORY_SCOPE_AGENT);
}
__device__ __forceinline__ void agent_storef(float* p, float v) {
    __hip_atomic_store(p, v, __ATOMIC_RELAXED, __HIP_MEMORY_SCOPE_AGENT);
}

// One ordinary launch, 16 blocks. Math (batch-separable, rank-1 since z>=0):
//   z[p], p = v*128+t
//   A[q]   = sum_f wth[f] * z[f*QQ + q]
//   Zp[q'] = sum_k max(wvd[k],0) * z[64q'+k];  Zn analog with min
//   S      = sum_q A[q] * (A[q]>=0 ? Zp[q] : Zn[q])
//   pooled[c] = Zmean*(S*gw[c]+1) + convh_b[c]; logits -> softmax -> out
// Last-arriver block per batch (device-scope ticket) runs the head.
__global__ __launch_bounds__(NTH) void ar_onepass(
    const float* __restrict__ joint, const float* __restrict__ vel,
    const float* __restrict__ vc1_w, const float* __restrict__ vc1_b,
    const float* __restrict__ vc2_w, const float* __restrict__ vc2_b,
    const float* __restrict__ sc1_w, const float* __restrict__ sc1_b,
    const float* __restrict__ sc2_w, const float* __restrict__ sc2_b,
    const float* __restrict__ w_theta, const float* __restrict__ w_void,
    const float* __restrict__ w_g,
    const float* __restrict__ convh_w, const float* __restrict__ convh_b,
    const float* __restrict__ lin_w, const float* __restrict__ lin_b,
    float* __restrict__ out, float* __restrict__ ws)
{
    const int blk = blockIdx.x;
    const int b = blk >> 3;        // batch
    const int g = blk & 7;         // chunk within batch
    const int tid = threadIdx.x;
    const int lane = tid & 63, wave = tid >> 6;

    __shared__ float Ap[QQ], Zp[QQ], Zn[QQ];
    __shared__ float wth[FF], wvp[FF], wvn[FF];
    __shared__ float Zs;
    __shared__ int isLast;
    __shared__ float rs[4], rz[4];
    __shared__ float Svv, Zmm;
    __shared__ float pooled[CC];
    __shared__ float logits[NCLS], evals[NCLS];
    __shared__ float smax, sinv;

    for (int i = tid; i < QQ; i += NTH) { Ap[i] = 0.f; Zp[i] = 0.f; Zn[i] = 0.f; }
    if (tid == 0) { Zs = 0.f; isLast = 0; }
    if (tid < FF) {
        float w = w_void[tid];
        wvp[tid] = fmaxf(w, 0.f);
        wvn[tid] = fminf(w, 0.f);
        wth[tid] = w_theta[tid];
    }
    __syncthreads();

    const float v1w0 = vc1_w[0], v1w1 = vc1_w[1], v1w2 = vc1_w[2], v1w3 = vc1_w[3];
    const float s1w0 = sc1_w[0], s1w1 = sc1_w[1], s1w2 = sc1_w[2], s1w3 = sc1_w[3];
    const float v1b = vc1_b[0], v2w = vc2_w[0], v2b = vc2_b[0];
    const float s1b = sc1_b[0], s2w = sc2_w[0], s2b = sc2_b[0];

    // ---- Stage 1: this block's 1/8 of batch b's elements ----
    const float4* velb = (const float4*)(vel + (size_t)b * CC * TV);
    const float4* jntb = (const float4*)(joint + (size_t)b * CC * TV);

    float zacc = 0.f;
    const int iend = (g + 1) * CHUNK;
    for (int i = g * CHUNK + tid; i < iend; i += NTH) {
        float4 vA = velb[i];            float4 jA = jntb[i];
        float4 vB = velb[i + P4];       float4 jB = jntb[i + P4];
        float4 vC = velb[i + 2 * P4];   float4 jC = jntb[i + 2 * P4];
        float4 vD = velb[i + 3 * P4];   float4 jD = jntb[i + 3 * P4];

        float zv[4];
        {
            float vs, js;
            vs = v1b + vA.x * v1w0 + vB.x * v1w1 + vC.x * v1w2 + vD.x * v1w3;
            js = s1b + jA.x * s1w0 + jB.x * s1w1 + jC.x * s1w2 + jD.x * s1w3;
            zv[0] = fmaxf(v2w * vs + v2b, 0.f) + fmaxf(s2w * js + s2b, 0.f);
            vs = v1b + vA.y * v1w0 + vB.y * v1w1 + vC.y * v1w2 + vD.y * v1w3;
            js = s1b + jA.y * s1w0 + jB.y * s1w1 + jC.y * s1w2 + jD.y * s1w3;
            zv[1] = fmaxf(v2w * vs + v2b, 0.f) + fmaxf(s2w * js + s2b, 0.f);
            vs = v1b + vA.z * v1w0 + vB.z * v1w1 + vC.z * v1w2 + vD.z * v1w3;
            js = s1b + jA.z * s1w0 + jB.z * s1w1 + jC.z * s1w2 + jD.z * s1w3;
            zv[2] = fmaxf(v2w * vs + v2b, 0.f) + fmaxf(s2w * js + s2b, 0.f);
            vs = v1b + vA.w * v1w0 + vB.w * v1w1 + vC.w * v1w2 + vD.w * v1w3;
            js = s1b + jA.w * s1w0 + jB.w * s1w1 + jC.w * s1w2 + jD.w * s1w3;
            zv[3] = fmaxf(v2w * vs + v2b, 0.f) + fmaxf(s2w * js + s2b, 0.f);
        }

        int r = 4 * i;
        int t = r / VV, v = r - t * VV;
        #pragma unroll
        for (int k = 0; k < 4; ++k) {
            int p = (v << 7) + t;
            float zz = zv[k];
            atomicAdd(&Ap[p % QQ], wth[p / QQ] * zz);
            atomicAdd(&Zp[p >> 6], wvp[p & 63] * zz);
            atomicAdd(&Zn[p >> 6], wvn[p & 63] * zz);
            zacc += zz;
            if (++v == VV) { v = 0; ++t; }
        }
    }
    #pragma unroll
    for (int off = 32; off > 0; off >>= 1) zacc += __shfl_down(zacc, off);
    if (lane == 0) atomicAdd(&Zs, zacc);
    __syncthreads();

    // ---- publish slot (agent scope), then ticket ----
    float* slot = ws + (size_t)blk * SLOTF;
    for (int i = tid; i < QQ; i += NTH) {
        agent_storef(slot + i,          Ap[i]);
        agent_storef(slot + QQ + i,     Zp[i]);
        agent_storef(slot + 2 * QQ + i, Zn[i]);
    }
    if (tid == 0) agent_storef(slot + 3 * QQ, Zs);
    __syncthreads();

    unsigned* cnt = (unsigned*)(ws + BB * GB * SLOTF) + b;
    if (tid == 0) {
        __threadfence();  // device-scope order: slot stores before ticket
        unsigned old = __hip_atomic_fetch_add(cnt, 1u, __ATOMIC_ACQ_REL,
                                              __HIP_MEMORY_SCOPE_AGENT);
        if (old == (unsigned)(GB - 1) || old == POISON + (unsigned)(GB - 1)) {
            isLast = 1;
            __hip_atomic_store(cnt, 0u, __ATOMIC_RELAXED, __HIP_MEMORY_SCOPE_AGENT);
        }
    }
    __syncthreads();
    if (!isLast) return;

    // ---- Stage 2 (finisher only): reduce 8 slots, head, softmax ----
    const float* base = ws + (size_t)b * GB * SLOTF;
    float sq = 0.f, zq = 0.f;
    if (tid < QQ) {
        float a = 0.f, zp = 0.f, zn = 0.f;
        #pragma unroll
        for (int gg = 0; gg < GB; ++gg) {
            const float* sl = base + gg * SLOTF;
            a  += agent_loadf(sl + tid);
            zp += agent_loadf(sl + QQ + tid);
            zn += agent_loadf(sl + 2 * QQ + tid);
        }
        sq = a * (a >= 0.f ? zp : zn);
    }
    if (tid < GB) zq = agent_loadf(base + tid * SLOTF + 3 * QQ);

    #pragma unroll
    for (int off = 32; off > 0; off >>= 1) {
        sq += __shfl_down(sq, off);
        zq += __shfl_down(zq, off);
    }
    if (lane == 0) { rs[wave] = sq; rz[wave] = zq; }
    __syncthreads();
    if (tid == 0) {
        Svv = rs[0] + rs[1] + rs[2] + rs[3];
        Zmm = (rz[0] + rz[1] + rz[2] + rz[3]) / (float)TV;
    }
    __syncthreads();

    {   // gw[c] = sum_f convh_w[c,f]*w_g[f]; wave index = c
        float gv = convh_w[wave * FF + lane] * w_g[lane];
        #pragma unroll
        for (int off = 32; off > 0; off >>= 1) gv += __shfl_down(gv, off);
        if (lane == 0) pooled[wave] = Zmm * (Svv * gv + 1.0f) + convh_b[wave];
    }
    __syncthreads();

    if (tid < NCLS) {
        float lg = lin_b[tid];
        #pragma unroll
        for (int c = 0; c < CC; ++c) lg += lin_w[tid * CC + c] * pooled[c];
        logits[tid] = lg;
    }
    __syncthreads();
    if (wave == 0) {
        float m = -1e30f;
        for (int n = lane; n < NCLS; n += 64) m = fmaxf(m, logits[n]);
        #pragma unroll
        for (int off = 32; off > 0; off >>= 1) m = fmaxf(m, __shfl_down(m, off));
        if (lane == 0) smax = m;
    }
    __syncthreads();
    if (tid < NCLS) evals[tid] = expf(logits[tid] - smax);
    __syncthreads();
    if (wave == 0) {
        float s = 0.f;
        for (int n = lane; n < NCLS; n += 64) s += evals[n];
        #pragma unroll
        for (int off = 32; off > 0; off >>= 1) s += __shfl_down(s, off);
        if (lane == 0) sinv = 1.0f / s;
    }
    __syncthreads();
    if (tid < NCLS) out[b * NCLS + tid] = evals[tid] * sinv;
}

extern "C" void kernel_launch(void* const* d_in, const int* in_sizes, int n_in,
                              void* d_out, int out_size, void* d_ws, size_t ws_size,
                              hipStream_t stream) {
    const float* joint  = (const float*)d_in[0];
    const float* vel    = (const float*)d_in[1];
    const float* vc1_w  = (const float*)d_in[2];
    const float* vc1_b  = (const float*)d_in[3];
    const float* vc2_w  = (const float*)d_in[4];
    const float* vc2_b  = (const float*)d_in[5];
    const float* sc1_w  = (const float*)d_in[6];
    const float* sc1_b  = (const float*)d_in[7];
    const float* sc2_w  = (const float*)d_in[8];
    const float* sc2_b  = (const float*)d_in[9];
    const float* w_theta = (const float*)d_in[10];
    const float* w_void  = (const float*)d_in[11];
    const float* w_g     = (const float*)d_in[12];
    const float* convh_w = (const float*)d_in[13];
    const float* convh_b = (const float*)d_in[14];
    const float* lin_w   = (const float*)d_in[15];
    const float* lin_b   = (const float*)d_in[16];
    float* out = (float*)d_out;
    float* ws  = (float*)d_ws;

    ar_onepass<<<BB * GB, NTH, 0, stream>>>(joint, vel, vc1_w, vc1_b, vc2_w, vc2_b,
                                            sc1_w, sc1_b, sc2_w, sc2_b,
                                            w_theta, w_void, w_g,
                                            convh_w, convh_b, lin_w, lin_b,
                                            out, ws);
}

// Round 7
// 14.721 us; speedup vs baseline: 2.6592x; 1.0167x over previous
//
#include <hip/hip_runtime.h>

#define BB 2
#define CC 4
#define TT 128
#define VV 67
#define FF 64
#define NCLS 100
#define TV 8576        // T*V
#define QQ 134         // TV/64
#define HB 2           // blocks (t-halves) per batch
#define NTH 1024
#define P4 (TV / 4)    // 2144 float4 per channel plane
#define H4 (P4 / HB)   // 1072 float4 per half per plane
#define PAD 65         // LDS row pitch (odd -> conflict-free Z-pass)
#define SLOTF 272      // per-block slot floats (269 used)
#define POISON 0xAAAAAAAAu

__device__ __forceinline__ float agent_loadf(const float* p) {
    return __hip_atomic_load(p, __ATOMIC_RELAXED, __HIP_MEMORY_SCOPE_AGENT);
}
__device__ __forceinline__ void agent_storef(float* p, float v) {
    __hip_atomic_store(p, v, __ATOMIC_RELAXED, __HIP_MEMORY_SCOPE_AGENT);
}

// One launch, 4 blocks: blk = b*2 + h, h = t-half. Math (rank-1 since z>=0):
//   z[p], p = v*128+t.  Block h covers t in [64h, 64h+64) -> LDS zs[v][t&63].
//   A[q]   = sum_f wth[f]*z[f*134+q]      (both halves contribute -> summed slot A)
//   q' = p>>6 = 2v + h  -> Zp/Zn[q'] partials are PARITY-DISJOINT per half:
//   Zp_h[v] = sum_tl max(wvd[tl],0)*zs[v][tl]   (q'=2v+h), Zn analog.
//   S = sum_q' A[q']*(A[q']>=0 ? Zp[q'] : Zn[q'])
//   pooled[c] = Zmean*(S*gw[c]+1)+convh_b[c]; logits->softmax->out.
// Last-arriver block per batch (poison-aware ticket) runs the head.
__global__ __launch_bounds__(NTH) void ar_half(
    const float* __restrict__ joint, const float* __restrict__ vel,
    const float* __restrict__ vc1_w, const float* __restrict__ vc1_b,
    const float* __restrict__ vc2_w, const float* __restrict__ vc2_b,
    const float* __restrict__ sc1_w, const float* __restrict__ sc1_b,
    const float* __restrict__ sc2_w, const float* __restrict__ sc2_b,
    const float* __restrict__ w_theta, const float* __restrict__ w_void,
    const float* __restrict__ w_g,
    const float* __restrict__ convh_w, const float* __restrict__ convh_b,
    const float* __restrict__ lin_w, const float* __restrict__ lin_b,
    float* __restrict__ out, float* __restrict__ ws)
{
    const int blk = blockIdx.x;
    const int b = blk >> 1;
    const int h = blk & 1;
    const int tid = threadIdx.x;
    const int lane = tid & 63, wave = tid >> 6;

    __shared__ float zs[VV * PAD];      // 4355 floats
    __shared__ float wth[FF], wvp[FF], wvn[FF];
    __shared__ float Zsl;
    __shared__ int isLast;
    __shared__ float rs[16], rz[16];
    __shared__ float Svv, Zmm;
    __shared__ float pooled[CC];
    __shared__ float logits[NCLS], evals[NCLS];
    __shared__ float smax, sinv;

    if (tid < FF) {
        float w = w_void[tid];
        wth[tid] = w_theta[tid];
        wvp[tid] = fmaxf(w, 0.f);
        wvn[tid] = fminf(w, 0.f);
    }
    if (tid == 0) { Zsl = 0.f; isLast = 0; }
    __syncthreads();

    const float v1w0 = vc1_w[0], v1w1 = vc1_w[1], v1w2 = vc1_w[2], v1w3 = vc1_w[3];
    const float s1w0 = sc1_w[0], s1w1 = sc1_w[1], s1w2 = sc1_w[2], s1w3 = sc1_w[3];
    const float v1b = vc1_b[0], v2w = vc2_w[0], v2b = vc2_b[0];
    const float s1b = sc1_b[0], s2w = sc2_w[0], s2b = sc2_b[0];

    // ---- Stage 1: z for this t-half into LDS (zs[v][t&63]), fused Zsum ----
    const float4* velb = (const float4*)(vel + (size_t)b * CC * TV);
    const float4* jntb = (const float4*)(joint + (size_t)b * CC * TV);

    float zacc = 0.f;
    const int iend = (h + 1) * H4;
    for (int i = h * H4 + tid; i < iend; i += NTH) {
        float4 vA = velb[i];            float4 jA = jntb[i];
        float4 vB = velb[i + P4];       float4 jB = jntb[i + P4];
        float4 vC = velb[i + 2 * P4];   float4 jC = jntb[i + 2 * P4];
        float4 vD = velb[i + 3 * P4];   float4 jD = jntb[i + 3 * P4];

        float zv[4];
        {
            float vs, js;
            vs = v1b + vA.x * v1w0 + vB.x * v1w1 + vC.x * v1w2 + vD.x * v1w3;
            js = s1b + jA.x * s1w0 + jB.x * s1w1 + jC.x * s1w2 + jD.x * s1w3;
            zv[0] = fmaxf(v2w * vs + v2b, 0.f) + fmaxf(s2w * js + s2b, 0.f);
            vs = v1b + vA.y * v1w0 + vB.y * v1w1 + vC.y * v1w2 + vD.y * v1w3;
            js = s1b + jA.y * s1w0 + jB.y * s1w1 + jC.y * s1w2 + jD.y * s1w3;
            zv[1] = fmaxf(v2w * vs + v2b, 0.f) + fmaxf(s2w * js + s2b, 0.f);
            vs = v1b + vA.z * v1w0 + vB.z * v1w1 + vC.z * v1w2 + vD.z * v1w3;
            js = s1b + jA.z * s1w0 + jB.z * s1w1 + jC.z * s1w2 + jD.z * s1w3;
            zv[2] = fmaxf(v2w * vs + v2b, 0.f) + fmaxf(s2w * js + s2b, 0.f);
            vs = v1b + vA.w * v1w0 + vB.w * v1w1 + vC.w * v1w2 + vD.w * v1w3;
            js = s1b + jA.w * s1w0 + jB.w * s1w1 + jC.w * s1w2 + jD.w * s1w3;
            zv[3] = fmaxf(v2w * vs + v2b, 0.f) + fmaxf(s2w * js + s2b, 0.f);
        }

        int r = 4 * i;
        int t = r / VV, v = r - t * VV;
        int tl = t & 63;
        #pragma unroll
        for (int k = 0; k < 4; ++k) {
            zs[v * PAD + tl] = zv[k];
            zacc += zv[k];
            if (++v == VV) { v = 0; tl = (++t) & 63; }
        }
    }
    #pragma unroll
    for (int off = 32; off > 0; off >>= 1) zacc += __shfl_down(zacc, off);
    if (lane == 0) atomicAdd(&Zsl, zacc);
    __syncthreads();

    // ---- A/Z passes on disjoint thread ranges, publish straight to slot ----
    float* slot = ws + (size_t)blk * SLOTF;
    if (tid < QQ) {
        // A_h[q] = sum over f with ((p>>6)&1)==h of wth[f]*z[p], p=f*134+q
        const int q = tid;
        float acc = 0.f;
        #pragma unroll
        for (int f = 0; f < FF; ++f) {
            int p = f * QQ + q;
            if (((p >> 6) & 1) == h)
                acc += wth[f] * zs[(p >> 7) * PAD + (p & 63)];
        }
        agent_storef(slot + q, acc);
    } else if (tid < QQ + VV) {
        // Zp_h[v], Zn_h[v] for q' = 2v+h
        const int v = tid - QQ;
        float zp = 0.f, zn = 0.f;
        const float* zrow = zs + v * PAD;
        #pragma unroll
        for (int tl = 0; tl < 64; ++tl) {
            float zz = zrow[tl];
            zp += wvp[tl] * zz;
            zn += wvn[tl] * zz;
        }
        agent_storef(slot + QQ + v, zp);
        agent_storef(slot + QQ + VV + v, zn);
    } else if (tid == QQ + VV) {
        agent_storef(slot + QQ + 2 * VV, Zsl);   // index 268
    }
    __syncthreads();

    // ---- ticket: last arriver of this batch finishes ----
    unsigned* cnt = (unsigned*)(ws + (size_t)BB * HB * SLOTF) + b;
    if (tid == 0) {
        __threadfence();
        unsigned old = __hip_atomic_fetch_add(cnt, 1u, __ATOMIC_ACQ_REL,
                                              __HIP_MEMORY_SCOPE_AGENT);
        if (old == (unsigned)(HB - 1) || old == POISON + (unsigned)(HB - 1)) {
            isLast = 1;
            __hip_atomic_store(cnt, 0u, __ATOMIC_RELAXED, __HIP_MEMORY_SCOPE_AGENT);
        }
    }
    __syncthreads();
    if (!isLast) return;

    // ---- finisher: S, Zmean, head, softmax ----
    const float* s0 = ws + (size_t)(b * HB) * SLOTF;
    const float* s1 = s0 + SLOTF;

    float sq = 0.f, zq = 0.f;
    if (tid < QQ) {
        float a = agent_loadf(s0 + tid) + agent_loadf(s1 + tid);
        const float* sh = (tid & 1) ? s1 : s0;   // q' parity -> owning half
        int vv = tid >> 1;
        float zp = agent_loadf(sh + QQ + vv);
        float zn = agent_loadf(sh + QQ + VV + vv);
        sq = a * (a >= 0.f ? zp : zn);
    }
    if (tid < HB) zq = agent_loadf(((tid ? s1 : s0) + QQ + 2 * VV));

    #pragma unroll
    for (int off = 32; off > 0; off >>= 1) {
        sq += __shfl_down(sq, off);
        zq += __shfl_down(zq, off);
    }
    if (lane == 0) { rs[wave] = sq; rz[wave] = zq; }
    __syncthreads();
    if (tid == 0) {
        float aS = 0.f, aZ = 0.f;
        #pragma unroll
        for (int w = 0; w < 16; ++w) { aS += rs[w]; aZ += rz[w]; }
        Svv = aS;
        Zmm = aZ / (float)TV;
    }
    __syncthreads();

    if (wave < CC) {   // gw[c] = sum_f convh_w[c,f]*w_g[f], wave = c
        float gv = convh_w[wave * FF + lane] * w_g[lane];
        #pragma unroll
        for (int off = 32; off > 0; off >>= 1) gv += __shfl_down(gv, off);
        if (lane == 0) pooled[wave] = Zmm * (Svv * gv + 1.0f) + convh_b[wave];
    }
    __syncthreads();

    if (tid < NCLS) {
        float lg = lin_b[tid];
        #pragma unroll
        for (int c = 0; c < CC; ++c) lg += lin_w[tid * CC + c] * pooled[c];
        logits[tid] = lg;
    }
    __syncthreads();
    if (wave == 0) {
        float m = -1e30f;
        for (int n = lane; n < NCLS; n += 64) m = fmaxf(m, logits[n]);
        #pragma unroll
        for (int off = 32; off > 0; off >>= 1) m = fmaxf(m, __shfl_down(m, off));
        if (lane == 0) smax = m;
    }
    __syncthreads();
    if (tid < NCLS) evals[tid] = __expf(logits[tid] - smax);
    __syncthreads();
    if (wave == 0) {
        float s = 0.f;
        for (int n = lane; n < NCLS; n += 64) s += evals[n];
        #pragma unroll
        for (int off = 32; off > 0; off >>= 1) s += __shfl_down(s, off);
        if (lane == 0) sinv = 1.0f / s;
    }
    __syncthreads();
    if (tid < NCLS) out[b * NCLS + tid] = evals[tid] * sinv;
}

extern "C" void kernel_launch(void* const* d_in, const int* in_sizes, int n_in,
                              void* d_out, int out_size, void* d_ws, size_t ws_size,
                              hipStream_t stream) {
    const float* joint  = (const float*)d_in[0];
    const float* vel    = (const float*)d_in[1];
    const float* vc1_w  = (const float*)d_in[2];
    const float* vc1_b  = (const float*)d_in[3];
    const float* vc2_w  = (const float*)d_in[4];
    const float* vc2_b  = (const float*)d_in[5];
    const float* sc1_w  = (const float*)d_in[6];
    const float* sc1_b  = (const float*)d_in[7];
    const float* sc2_w  = (const float*)d_in[8];
    const float* sc2_b  = (const float*)d_in[9];
    const float* w_theta = (const float*)d_in[10];
    const float* w_void  = (const float*)d_in[11];
    const float* w_g     = (const float*)d_in[12];
    const float* convh_w = (const float*)d_in[13];
    const float* convh_b = (const float*)d_in[14];
    const float* lin_w   = (const float*)d_in[15];
    const float* lin_b   = (const float*)d_in[16];
    float* out = (float*)d_out;
    float* ws  = (float*)d_ws;

    ar_half<<<BB * HB, NTH, 0, stream>>>(joint, vel, vc1_w, vc1_b, vc2_w, vc2_b,
                                         sc1_w, sc1_b, sc2_w, sc2_b,
                                         w_theta, w_void, w_g,
                                         convh_w, convh_b, lin_w, lin_b,
                                         out, ws);
}

// Round 8
// 11.719 us; speedup vs baseline: 3.3404x; 1.2562x over previous
//
#include <hip/hip_runtime.h>

#define BB 2
#define CC 4
#define TT 128
#define VV 67
#define FF 64
#define NCLS 100
#define TV 8576   // T*V == V*T
#define QQ 134    // TV / 64

// Padded LDS accessor for z stored at p = v*128 + t:
// idx(p) = v*129 + t = p + (p>>7); transpose store + strided reads conflict-free.
#define ZIDX(p) ((p) + ((p) >> 7))
#define ZLDS (TV + VV)   // 8643 floats

// Whole model, one kernel, block b = batch b (batch-separable; rank-1 scores
// since z >= 0):
//   z[p] = relu(vc2*(sum_c vel*vc1)+vc2b) + relu(sc2*(sum_c joint*sc1)+sc2b)
//   A[q] = sum_f wth[f]*z[f*QQ+q]
//   S    = sum_j relu(wvd[j&63]*A[j>>6])*z[j]
//   pooled[c] = Zmean*(S*gw[c]+1) + convh_b[c];  logits -> softmax -> out
__global__ __launch_bounds__(1024) void ar_fused(
    const float* __restrict__ joint, const float* __restrict__ vel,
    const float* __restrict__ vc1_w, const float* __restrict__ vc1_b,
    const float* __restrict__ vc2_w, const float* __restrict__ vc2_b,
    const float* __restrict__ sc1_w, const float* __restrict__ sc1_b,
    const float* __restrict__ sc2_w, const float* __restrict__ sc2_b,
    const float* __restrict__ w_theta, const float* __restrict__ w_void,
    const float* __restrict__ w_g,
    const float* __restrict__ convh_w, const float* __restrict__ convh_b,
    const float* __restrict__ lin_w, const float* __restrict__ lin_b,
    float* __restrict__ out)
{
    const int b = blockIdx.x;
    const int tid = threadIdx.x;
    const int lane = tid & 63, wave = tid >> 6;

    __shared__ float zs[ZLDS];            // 34.6 KB
    __shared__ float wth[FF], wvd[FF];
    __shared__ float Apart[4][QQ];
    __shared__ float A[QQ];
    __shared__ float redS[16], redZ[16];
    __shared__ float Sv, Zm;
    __shared__ float pooled[CC];
    __shared__ float logits[NCLS], evals[NCLS];
    __shared__ float smax, sinv;

    if (tid < FF) { wth[tid] = w_theta[tid]; wvd[tid] = w_void[tid]; }

    const float v1w0 = vc1_w[0], v1w1 = vc1_w[1], v1w2 = vc1_w[2], v1w3 = vc1_w[3];
    const float s1w0 = sc1_w[0], s1w1 = sc1_w[1], s1w2 = sc1_w[2], s1w3 = sc1_w[3];
    const float v1b = vc1_b[0], v2w = vc2_w[0], v2b = vc2_b[0];
    const float s1b = sc1_b[0], s2w = sc2_w[0], s2b = sc2_b[0];

    // ---- Phase 1: z into LDS (p = v*T + t), fused Zsum ----
    const float4* velb = (const float4*)(vel + (size_t)b * CC * TV);
    const float4* jntb = (const float4*)(joint + (size_t)b * CC * TV);
    const int P4 = TV / 4;   // 2144

    float zacc = 0.0f;
    for (int i = tid; i < P4; i += 1024) {
        float4 vA = velb[i];            float4 jA = jntb[i];
        float4 vB = velb[i + P4];       float4 jB = jntb[i + P4];
        float4 vC = velb[i + 2 * P4];   float4 jC = jntb[i + 2 * P4];
        float4 vD = velb[i + 3 * P4];   float4 jD = jntb[i + 3 * P4];

        float zv[4];
        {
            float vs, js;
            vs = v1b + vA.x * v1w0 + vB.x * v1w1 + vC.x * v1w2 + vD.x * v1w3;
            js = s1b + jA.x * s1w0 + jB.x * s1w1 + jC.x * s1w2 + jD.x * s1w3;
            zv[0] = fmaxf(v2w * vs + v2b, 0.f) + fmaxf(s2w * js + s2b, 0.f);
            vs = v1b + vA.y * v1w0 + vB.y * v1w1 + vC.y * v1w2 + vD.y * v1w3;
            js = s1b + jA.y * s1w0 + jB.y * s1w1 + jC.y * s1w2 + jD.y * s1w3;
            zv[1] = fmaxf(v2w * vs + v2b, 0.f) + fmaxf(s2w * js + s2b, 0.f);
            vs = v1b + vA.z * v1w0 + vB.z * v1w1 + vC.z * v1w2 + vD.z * v1w3;
            js = s1b + jA.z * s1w0 + jB.z * s1w1 + jC.z * s1w2 + jD.z * s1w3;
            zv[2] = fmaxf(v2w * vs + v2b, 0.f) + fmaxf(s2w * js + s2b, 0.f);
            vs = v1b + vA.w * v1w0 + vB.w * v1w1 + vC.w * v1w2 + vD.w * v1w3;
            js = s1b + jA.w * s1w0 + jB.w * s1w1 + jC.w * s1w2 + jD.w * s1w3;
            zv[3] = fmaxf(v2w * vs + v2b, 0.f) + fmaxf(s2w * js + s2b, 0.f);
        }

        int r = 4 * i;
        int t = r / VV, v = r - t * VV;
        #pragma unroll
        for (int k = 0; k < 4; ++k) {
            int p = (v << 7) + t;
            zs[ZIDX(p)] = zv[k];
            zacc += zv[k];
            if (++v == VV) { v = 0; ++t; }
        }
    }
    __syncthreads();

    // ---- Phase 2: A[q] = sum_f wth[f]*z[f*QQ+q], 536-thread split ----
    if (tid < 4 * QQ) {
        int q = tid % QQ, g = tid / QQ;
        float acc = 0.0f;
        #pragma unroll
        for (int k = 0; k < 16; ++k) {
            int p = (g * 16 + k) * QQ + q;
            acc += wth[g * 16 + k] * zs[ZIDX(p)];
        }
        Apart[g][q] = acc;
    }
    __syncthreads();
    if (tid < QQ)
        A[tid] = (Apart[0][tid] + Apart[1][tid]) + (Apart[2][tid] + Apart[3][tid]);
    __syncthreads();

    // ---- Phase 3: S = sum_j relu(wvd[j&63]*A[j>>6]) * z[j]; finish Zsum ----
    float sS = 0.0f;
    for (int j = tid; j < TV; j += 1024) {
        float u = wvd[j & 63] * A[j >> 6];
        sS += fmaxf(u, 0.0f) * zs[ZIDX(j)];
    }
    #pragma unroll
    for (int off = 32; off > 0; off >>= 1) {
        sS += __shfl_down(sS, off);
        zacc += __shfl_down(zacc, off);
    }
    if (lane == 0) { redS[wave] = sS; redZ[wave] = zacc; }
    __syncthreads();
    if (tid == 0) {
        float aS = 0.f, aZ = 0.f;
        #pragma unroll
        for (int w = 0; w < 16; ++w) { aS += redS[w]; aZ += redZ[w]; }
        Sv = aS;
        Zm = aZ / (float)TV;
    }
    __syncthreads();

    // ---- Phase 4: pooled -> logits -> softmax -> out (wave-parallel) ----
    if (wave < CC) {   // gw[c] = sum_f convh_w[c,f]*w_g[f]; wave = c
        float gv = convh_w[wave * FF + lane] * w_g[lane];
        #pragma unroll
        for (int off = 32; off > 0; off >>= 1) gv += __shfl_down(gv, off);
        if (lane == 0) pooled[wave] = Zm * (Sv * gv + 1.0f) + convh_b[wave];
    }
    __syncthreads();

    if (tid < NCLS) {
        float lg = lin_b[tid];
        #pragma unroll
        for (int c = 0; c < CC; ++c) lg += lin_w[tid * CC + c] * pooled[c];
        logits[tid] = lg;
    }
    __syncthreads();
    if (wave == 0) {
        float m = -1e30f;
        for (int n = lane; n < NCLS; n += 64) m = fmaxf(m, logits[n]);
        #pragma unroll
        for (int off = 32; off > 0; off >>= 1) m = fmaxf(m, __shfl_down(m, off));
        if (lane == 0) smax = m;
    }
    __syncthreads();
    if (tid < NCLS) evals[tid] = __expf(logits[tid] - smax);
    __syncthreads();
    if (wave == 0) {
        float s = 0.f;
        for (int n = lane; n < NCLS; n += 64) s += evals[n];
        #pragma unroll
        for (int off = 32; off > 0; off >>= 1) s += __shfl_down(s, off);
        if (lane == 0) sinv = 1.0f / s;
    }
    __syncthreads();
    if (tid < NCLS) out[b * NCLS + tid] = evals[tid] * sinv;
}

extern "C" void kernel_launch(void* const* d_in, const int* in_sizes, int n_in,
                              void* d_out, int out_size, void* d_ws, size_t ws_size,
                              hipStream_t stream) {
    const float* joint  = (const float*)d_in[0];
    const float* vel    = (const float*)d_in[1];
    const float* vc1_w  = (const float*)d_in[2];
    const float* vc1_b  = (const float*)d_in[3];
    const float* vc2_w  = (const float*)d_in[4];
    const float* vc2_b  = (const float*)d_in[5];
    const float* sc1_w  = (const float*)d_in[6];
    const float* sc1_b  = (const float*)d_in[7];
    const float* sc2_w  = (const float*)d_in[8];
    const float* sc2_b  = (const float*)d_in[9];
    const float* w_theta = (const float*)d_in[10];
    const float* w_void  = (const float*)d_in[11];
    const float* w_g     = (const float*)d_in[12];
    const float* convh_w = (const float*)d_in[13];
    const float* convh_b = (const float*)d_in[14];
    const float* lin_w   = (const float*)d_in[15];
    const float* lin_b   = (const float*)d_in[16];
    float* out = (float*)d_out;

    ar_fused<<<BB, 1024, 0, stream>>>(joint, vel, vc1_w, vc1_b, vc2_w, vc2_b,
                                      sc1_w, sc1_b, sc2_w, sc2_b,
                                      w_theta, w_void, w_g,
                                      convh_w, convh_b, lin_w, lin_b, out);
}